// Round 5
// baseline (385.983 us; speedup 1.0000x reference)
//
#include <hip/hip_runtime.h>

#define B_ 16
#define P_ 12
#define N_ 2048
#define H_ 64
#define E_ 16384
#define NH_ (N_*H_)            // 131072
#define NG_ (B_*P_)            // 192

// ---------------- fused: per-plane LN1 stats (blocks 0..191) + CSR build (block 192) ----
__global__ __launch_bounds__(1024) void k_stats_csr(const float* __restrict__ x,
                                                    const int* __restrict__ ew,
                                                    float* __restrict__ mean1,
                                                    float* __restrict__ rstd1,
                                                    int* __restrict__ rowPtr,
                                                    int* __restrict__ csrSrc,
                                                    float* __restrict__ csrW) {
    __shared__ int   sDeg[N_];
    __shared__ int   sA[N_];
    __shared__ int   sB[N_];
    __shared__ float sDinv[N_];
    __shared__ int   sFlag;
    __shared__ float ls[16], lq[16];
    int tid = threadIdx.x;
    if (blockIdx.x < NG_) {
        // ---- LN1 stats for one (b,p) plane ----
        int g = blockIdx.x;
        const float4* xg = (const float4*)(x + (size_t)g * NH_);
        float s = 0.f, q = 0.f;
        #pragma unroll 8
        for (int i = 0; i < 32; ++i) {
            float4 v = xg[i*1024 + tid];
            s += v.x + v.y + v.z + v.w;
            q += v.x*v.x + v.y*v.y + v.z*v.z + v.w*v.w;
        }
        for (int off = 32; off; off >>= 1) { s += __shfl_down(s, off); q += __shfl_down(q, off); }
        int wid = tid >> 6, lane = tid & 63;
        if (!lane) { ls[wid] = s; lq[wid] = q; }
        __syncthreads();
        if (!tid) {
            float S = 0.f, Q = 0.f;
            #pragma unroll
            for (int i = 0; i < 16; ++i) { S += ls[i]; Q += lq[i]; }
            float m = S * (1.0f/NH_);
            float v = Q * (1.0f/NH_) - m*m;
            mean1[g] = m;
            rstd1[g] = rsqrtf(v + 1e-5f);
        }
        return;
    }
    // ---- CSR build (single block) with int32/int64 detection ----
    if (!tid) sFlag = 1;
    for (int i = tid; i < N_; i += 1024) sDeg[i] = 0;
    __syncthreads();
    if (tid < 256) { if (ew[2*tid+1] != 0) atomicAnd(&sFlag, 0); }
    __syncthreads();
    int is64 = sFlag;
    for (int e = tid; e < E_; e += 1024) {
        int dst = is64 ? ew[2*(E_+e)] : ew[E_+e];
        atomicAdd(&sDeg[dst], 1);
    }
    __syncthreads();
    for (int i = tid; i < N_; i += 1024) {
        int d = sDeg[i];
        sDinv[i] = d > 0 ? rsqrtf((float)d) : 0.f;
        sA[i] = d;
    }
    __syncthreads();
    int* in = sA; int* out = sB;
    for (int st = 1; st < N_; st <<= 1) {
        for (int i = tid; i < N_; i += 1024) {
            int v = in[i];
            if (i >= st) v += in[i-st];
            out[i] = v;
        }
        __syncthreads();
        int* t = in; in = out; out = t;
    }
    for (int i = tid; i < N_; i += 1024) {
        int excl = in[i] - sDeg[i];
        rowPtr[i] = excl;
        out[i] = excl;
    }
    if (!tid) rowPtr[N_] = E_;
    __syncthreads();
    for (int e = tid; e < E_; e += 1024) {
        int src = is64 ? ew[2*e]       : ew[e];
        int dst = is64 ? ew[2*(E_+e)]  : ew[E_+e];
        int pos = atomicAdd(&out[dst], 1);
        csrSrc[pos] = src;
        csrW[pos] = sDinv[src] * sDinv[dst];
    }
}

// ---------------- finalize: partials -> mean/rstd per group (any cnt) ----------------
__global__ __launch_bounds__(64) void k_finalize(const float* __restrict__ partials, int cnt,
                                                 float* __restrict__ mean, float* __restrict__ rstd) {
    int g = blockIdx.x, lane = threadIdx.x;
    float s = 0.f, q = 0.f;
    for (int i = lane; i < cnt; i += 64) {
        s += partials[(g*cnt+i)*2];
        q += partials[(g*cnt+i)*2+1];
    }
    for (int off = 32; off; off >>= 1) { s += __shfl_down(s, off); q += __shfl_down(q, off); }
    if (!lane) {
        float m = s * (1.0f/NH_);
        float v = q * (1.0f/NH_) - m*m;
        mean[g] = m;
        rstd[g] = rsqrtf(v + 1e-5f);
    }
}

// ---------------- gather v4: phase-tiled for per-XCD L2 residency ----
// 4 phases x 1024 blocks. Phase = {b-group 0/1} x {p-half 0/1}.
// Within a phase: xcd = blk&7 -> b = bh*8+xcd (ONE b per XCD, 6 planes = ~3.5MB < 4MB L2).
// h2[b,p,n,h] = rstd*acc_p - mean*rstd*Bn + An
#define PH_ 6
__global__ __launch_bounds__(256) void k_gather(const float* __restrict__ x,
                                                const float* __restrict__ gw,
                                                const float* __restrict__ gb,
                                                const float* __restrict__ mean1,
                                                const float* __restrict__ rstd1,
                                                const int* __restrict__ rowPtr,
                                                const int* __restrict__ csrSrc,
                                                const float* __restrict__ csrW,
                                                float* __restrict__ h2,        // staged in d_out
                                                float* __restrict__ partials /*[192][128][2]*/) {
    int blk   = blockIdx.x & 1023;
    int phase = blockIdx.x >> 10;          // 0..3
    int bh    = phase & 1, ph = phase >> 1;
    int b     = bh*8 + (blk & 7);          // one b per XCD within a phase
    int chunk = blk >> 3;                  // 0..127, 16 nodes each
    int p0    = ph*PH_;
    int wid = threadIdx.x >> 6, lane = threadIdx.x & 63;
    __shared__ float s_rs[PH_], s_mrs[PH_];
    __shared__ float red[4][PH_][2];
    if (threadIdx.x < PH_) {
        float m = mean1[b*P_ + p0 + threadIdx.x], r = rstd1[b*P_ + p0 + threadIdx.x];
        s_rs[threadIdx.x] = r; s_mrs[threadIdx.x] = m*r;
    }
    __syncthreads();
    const float* xb = x + ((size_t)b*P_ + p0) * NH_;
    float sp[PH_], qp[PH_];
    #pragma unroll
    for (int p = 0; p < PH_; ++p) { sp[p] = 0.f; qp[p] = 0.f; }
    #pragma unroll
    for (int i = 0; i < 4; ++i) {
        int n  = chunk*16 + wid*4 + i;
        int r0 = rowPtr[n], r1 = rowPtr[n+1];
        float acc[PH_];
        #pragma unroll
        for (int p = 0; p < PH_; ++p) acc[p] = 0.f;
        float An = 0.f, Bn = 0.f;
        for (int j = r0; j < r1; ++j) {
            int   src = csrSrc[j];
            float w   = csrW[j];
            int   ro  = src*H_ + lane;
            float t   = w * gw[ro];
            Bn += t;
            An += w * gb[ro];
            #pragma unroll
            for (int p = 0; p < PH_; ++p)
                acc[p] += t * xb[(size_t)p*NH_ + ro];
        }
        size_t ob = ((size_t)b*P_ + p0)*NH_ + (size_t)n*H_ + lane;
        #pragma unroll
        for (int p = 0; p < PH_; ++p) {
            float val = s_rs[p]*acc[p] - s_mrs[p]*Bn + An;
            h2[ob + (size_t)p*NH_] = val;
            sp[p] += val; qp[p] += val*val;
        }
    }
    #pragma unroll
    for (int p = 0; p < PH_; ++p) {
        float s = sp[p], q = qp[p];
        for (int off = 32; off; off >>= 1) { s += __shfl_down(s, off); q += __shfl_down(q, off); }
        if (!lane) { red[wid][p][0] = s; red[wid][p][1] = q; }
    }
    __syncthreads();
    if (threadIdx.x < PH_*2) {
        int p = threadIdx.x >> 1, c = threadIdx.x & 1;
        float v = red[0][p][c] + red[1][p][c] + red[2][p][c] + red[3][p][c];
        partials[(((b*P_ + p0 + p) << 7) + chunk)*2 + c] = v;
    }
}

// ---------------- mix: LN2 + 1x1 conv over P, in place on d_out ----------------
__global__ __launch_bounds__(256) void k_mix(float* __restrict__ h2,   // in/out = d_out
                                             const float* __restrict__ tw,
                                             const float* __restrict__ tb,
                                             const float* __restrict__ cw,
                                             const float* __restrict__ cb,
                                             const float* __restrict__ mean2,
                                             const float* __restrict__ rstd2) {
    __shared__ float scw[P_*P_], scb[P_], sm[P_], sr[P_], srow[P_];
    int b     = blockIdx.x >> 7;
    int chunk = blockIdx.x & 127;
    int tid   = threadIdx.x;
    if (tid < P_*P_) scw[tid] = cw[tid];
    if (tid < P_) {
        scb[tid] = cb[tid];
        sm[tid]  = mean2[b*P_ + tid];
        sr[tid]  = rstd2[b*P_ + tid];
    }
    __syncthreads();
    if (tid < P_) {
        float rs = 0.f;
        #pragma unroll
        for (int p = 0; p < P_; ++p) rs += scw[tid*P_ + p];
        srow[tid] = rs;
    }
    __syncthreads();
    int elem4 = chunk*256 + tid;           // 0..32767 = NH_/4
    size_t base = (size_t)b * P_ * NH_;
    float4 v[P_];
    #pragma unroll
    for (int p = 0; p < P_; ++p) {
        float4 t = *(const float4*)(h2 + base + (size_t)p*NH_ + (size_t)elem4*4);
        float m = sm[p], r = sr[p];
        v[p].x = (t.x-m)*r; v[p].y = (t.y-m)*r; v[p].z = (t.z-m)*r; v[p].w = (t.w-m)*r;
    }
    float4 tw4 = *(const float4*)(tw + (size_t)elem4*4);
    float4 tb4 = *(const float4*)(tb + (size_t)elem4*4);
    #pragma unroll
    for (int q = 0; q < P_; ++q) {
        float4 a = {0.f,0.f,0.f,0.f};
        #pragma unroll
        for (int p = 0; p < P_; ++p) {
            float c = scw[q*P_ + p];
            a.x += c*v[p].x; a.y += c*v[p].y; a.z += c*v[p].z; a.w += c*v[p].w;
        }
        float rb = srow[q], cbq = scb[q];
        float4 o;
        o.x = tw4.x*a.x + tb4.x*rb + cbq;
        o.y = tw4.y*a.y + tb4.y*rb + cbq;
        o.z = tw4.z*a.z + tb4.z*rb + cbq;
        o.w = tw4.w*a.w + tb4.w*rb + cbq;
        *(float4*)(h2 + base + (size_t)q*NH_ + (size_t)elem4*4) = o;
    }
}

extern "C" void kernel_launch(void* const* d_in, const int* in_sizes, int n_in,
                              void* d_out, int out_size, void* d_ws, size_t ws_size,
                              hipStream_t stream) {
    const float* x  = (const float*)d_in[0];
    const int*   ew = (const int*)d_in[1];
    const float* gw = (const float*)d_in[2];
    const float* gb = (const float*)d_in[3];
    const float* tw = (const float*)d_in[4];
    const float* tb = (const float*)d_in[5];
    const float* cw = (const float*)d_in[6];
    const float* cb = (const float*)d_in[7];
    float* out = (float*)d_out;
    float* wf  = (float*)d_ws;

    // ws layout (floats):
    // mean1[192]@0 rstd1[192]@192 mean2[192]@384 rstd2[192]@576
    // pC[192*128*2=49152]@768 -> end 49920
    // rowPtr(int)[2052]@49920 -> end 51972
    // csrSrc(int)[16384]@51972 -> 68356
    // csrW[16384]@68356 -> 84740 floats (~339 KB)
    float* mean1  = wf + 0;
    float* rstd1  = wf + 192;
    float* mean2  = wf + 384;
    float* rstd2  = wf + 576;
    float* pC     = wf + 768;
    int*   rowPtr = (int*)(wf + 49920);
    int*   csrSrc = (int*)(wf + 51972);
    float* csrW   = wf + 68356;

    k_stats_csr<<<NG_ + 1, 1024, 0, stream>>>(x, ew, mean1, rstd1, rowPtr, csrSrc, csrW);
    k_gather<<<4096, 256, 0, stream>>>(x, gw, gb, mean1, rstd1,
                                       rowPtr, csrSrc, csrW, out, pC);
    k_finalize<<<NG_, 64, 0, stream>>>(pC, 128, mean2, rstd2);
    k_mix<<<B_*128, 256, 0, stream>>>(out, tw, tb, cw, cb, mean2, rstd2);
}

// Round 7
// 379.823 us; speedup vs baseline: 1.0162x; 1.0162x over previous
//
#include <hip/hip_runtime.h>

#define B_ 16
#define P_ 12
#define N_ 2048
#define H_ 64
#define E_ 16384
#define NH_ (N_*H_)            // 131072
#define NG_ (B_*P_)            // 192

// ws layout (float offsets)
#define WS_MEAN1  0           // 192
#define WS_RSTD1  192         // 192
#define WS_PA     384         // 768*2 = 1536 -> ends 1920
#define WS_AG     2048        // 131072
#define WS_BG     133120      // 131072 -> ends 264192
#define WS_PC     264192      // 192*128*2 = 49152 -> ends 313344
#define WS_ROWPTR 313344      // 2049 ints -> ends 315393
#define WS_PAIR   315400      // 16384 int2 = 32768 ints -> ends 348168 (8B aligned)

// ---- k1: LN1 partial stats (blocks 0..767, 4 segs/plane) + CSR build (block 768) ----
__global__ __launch_bounds__(1024) void k_stats_csr(const float* __restrict__ x,
                                                    const int* __restrict__ ew,
                                                    float* __restrict__ pA,
                                                    int* __restrict__ rowPtr,
                                                    int2* __restrict__ pair) {
    __shared__ int   sDeg[N_];
    __shared__ int   sA[N_];
    __shared__ int   sB[N_];
    __shared__ float sDinv[N_];
    __shared__ int   sFlag;
    __shared__ float ls[16], lq[16];
    int tid = threadIdx.x;
    if (blockIdx.x < 768) {
        int g = blockIdx.x >> 2, seg = blockIdx.x & 3;
        const float4* xg = (const float4*)(x + (size_t)g * NH_);
        float s = 0.f, q = 0.f;
        int base = seg * 8192;
        #pragma unroll
        for (int i = 0; i < 8; ++i) {
            float4 v = xg[base + i*1024 + tid];
            s += v.x + v.y + v.z + v.w;
            q += v.x*v.x + v.y*v.y + v.z*v.z + v.w*v.w;
        }
        for (int off = 32; off; off >>= 1) { s += __shfl_down(s, off); q += __shfl_down(q, off); }
        int wid = tid >> 6, lane = tid & 63;
        if (!lane) { ls[wid] = s; lq[wid] = q; }
        __syncthreads();
        if (!tid) {
            float S = 0.f, Q = 0.f;
            #pragma unroll
            for (int i = 0; i < 16; ++i) { S += ls[i]; Q += lq[i]; }
            pA[blockIdx.x*2]   = S;
            pA[blockIdx.x*2+1] = Q;
        }
        return;
    }
    // ---- CSR build with int32/int64 detection ----
    if (!tid) sFlag = 1;
    for (int i = tid; i < N_; i += 1024) sDeg[i] = 0;
    __syncthreads();
    if (tid < 256) { if (ew[2*tid+1] != 0) atomicAnd(&sFlag, 0); }
    __syncthreads();
    int is64 = sFlag;
    for (int e = tid; e < E_; e += 1024) {
        int dst = is64 ? ew[2*(E_+e)] : ew[E_+e];
        atomicAdd(&sDeg[dst], 1);
    }
    __syncthreads();
    for (int i = tid; i < N_; i += 1024) {
        int d = sDeg[i];
        sDinv[i] = d > 0 ? rsqrtf((float)d) : 0.f;
        sA[i] = d;
    }
    __syncthreads();
    int* in = sA; int* out = sB;
    for (int st = 1; st < N_; st <<= 1) {
        for (int i = tid; i < N_; i += 1024) {
            int v = in[i];
            if (i >= st) v += in[i-st];
            out[i] = v;
        }
        __syncthreads();
        int* t = in; in = out; out = t;
    }
    for (int i = tid; i < N_; i += 1024) {
        int excl = in[i] - sDeg[i];
        rowPtr[i] = excl;
        out[i] = excl;
    }
    if (!tid) rowPtr[N_] = E_;
    __syncthreads();
    for (int e = tid; e < E_; e += 1024) {
        int src = is64 ? ew[2*e]       : ew[e];
        int dst = is64 ? ew[2*(E_+e)]  : ew[E_+e];
        int pos = atomicAdd(&out[dst], 1);
        int2 pr; pr.x = src; pr.y = __float_as_int(sDinv[src] * sDinv[dst]);
        pair[pos] = pr;
    }
}

// ---- k2: per-node A/B rows (blocks 0..511, wave per node) + LN1 finalize (block 512) ----
__global__ __launch_bounds__(256) void k_ab(const float* __restrict__ gw,
                                            const float* __restrict__ gb,
                                            const int* __restrict__ rowPtr,
                                            const int2* __restrict__ pair,
                                            const float* __restrict__ pA,
                                            float* __restrict__ Ag,
                                            float* __restrict__ Bg,
                                            float* __restrict__ mean1,
                                            float* __restrict__ rstd1) {
    int tid = threadIdx.x;
    if (blockIdx.x == 512) {
        if (tid < NG_) {
            float s = 0.f, q = 0.f;
            #pragma unroll
            for (int i = 0; i < 4; ++i) {
                s += pA[(tid*4+i)*2];
                q += pA[(tid*4+i)*2+1];
            }
            float m = s * (1.0f/NH_);
            float v = q * (1.0f/NH_) - m*m;
            mean1[tid] = m;
            rstd1[tid] = rsqrtf(v + 1e-5f);
        }
        return;
    }
    int wid = tid >> 6, lane = tid & 63;
    int n = blockIdx.x*4 + wid;
    int j = rowPtr[n], e = rowPtr[n+1];
    float A = 0.f, Bv = 0.f;
    for (; j < e; ++j) {
        int2 pr = pair[j];
        float w = __int_as_float(pr.y);
        int ro = pr.x*H_ + lane;
        A  += w * gb[ro];
        Bv += w * gw[ro];
    }
    Ag[n*H_ + lane] = A;
    Bg[n*H_ + lane] = Bv;
}

// ---- k3: gather v5 — 4 node-streams per wave, 12 planes, A/B hoisted ----
// h2[b,p,n,h] = rs[p]*acc_p - mrs[p]*B[n,h] + A[n,h]
__global__ __launch_bounds__(256) void k_gather(const float* __restrict__ x,
                                                const float* __restrict__ mean1,
                                                const float* __restrict__ rstd1,
                                                const int* __restrict__ rowPtr,
                                                const int2* __restrict__ pair,
                                                const float* __restrict__ Ag,
                                                const float* __restrict__ Bg,
                                                float* __restrict__ h2,
                                                float* __restrict__ pC) {
    int b     = blockIdx.x & 15;
    int chunk = blockIdx.x >> 4;           // 0..127
    int wid = threadIdx.x >> 6, lane = threadIdx.x & 63;
    __shared__ float s_rs[P_], s_mrs[P_];
    __shared__ float red[4][P_][2];
    if (threadIdx.x < P_) {
        float m = mean1[b*P_ + threadIdx.x], r = rstd1[b*P_ + threadIdx.x];
        s_rs[threadIdx.x] = r; s_mrs[threadIdx.x] = m*r;
    }
    __syncthreads();
    const float* xb = x + (size_t)b * P_ * NH_;
    int n0 = chunk*16 + wid*4;
    int r0 = rowPtr[n0], r1 = rowPtr[n0+1], r2 = rowPtr[n0+2],
        r3 = rowPtr[n0+3], r4 = rowPtr[n0+4];
    int j0 = r0, e0 = r1, j1 = r1, e1 = r2, j2 = r2, e2 = r3, j3 = r3, e3 = r4;
    float A0 = Ag[(n0+0)*H_+lane], B0 = Bg[(n0+0)*H_+lane];
    float A1 = Ag[(n0+1)*H_+lane], B1 = Bg[(n0+1)*H_+lane];
    float A2 = Ag[(n0+2)*H_+lane], B2 = Bg[(n0+2)*H_+lane];
    float A3 = Ag[(n0+3)*H_+lane], B3 = Bg[(n0+3)*H_+lane];
    float ac0[P_], ac1[P_], ac2[P_], ac3[P_];
    #pragma unroll
    for (int p = 0; p < P_; ++p) { ac0[p]=0.f; ac1[p]=0.f; ac2[p]=0.f; ac3[p]=0.f; }
    while ((j0 < e0) | (j1 < e1) | (j2 < e2) | (j3 < e3)) {
        if (j0 < e0) {
            int2 pr = pair[j0++]; float w = __int_as_float(pr.y); int ro = pr.x*H_ + lane;
            #pragma unroll
            for (int p = 0; p < P_; ++p) ac0[p] += w * xb[(size_t)p*NH_ + ro];
        }
        if (j1 < e1) {
            int2 pr = pair[j1++]; float w = __int_as_float(pr.y); int ro = pr.x*H_ + lane;
            #pragma unroll
            for (int p = 0; p < P_; ++p) ac1[p] += w * xb[(size_t)p*NH_ + ro];
        }
        if (j2 < e2) {
            int2 pr = pair[j2++]; float w = __int_as_float(pr.y); int ro = pr.x*H_ + lane;
            #pragma unroll
            for (int p = 0; p < P_; ++p) ac2[p] += w * xb[(size_t)p*NH_ + ro];
        }
        if (j3 < e3) {
            int2 pr = pair[j3++]; float w = __int_as_float(pr.y); int ro = pr.x*H_ + lane;
            #pragma unroll
            for (int p = 0; p < P_; ++p) ac3[p] += w * xb[(size_t)p*NH_ + ro];
        }
    }
    float sp[P_], qp[P_];
    #pragma unroll
    for (int p = 0; p < P_; ++p) { sp[p] = 0.f; qp[p] = 0.f; }
    size_t obb = (size_t)b*P_*NH_ + (size_t)n0*H_ + lane;
    #pragma unroll
    for (int p = 0; p < P_; ++p) {
        size_t op = obb + (size_t)p*NH_;
        float v0 = s_rs[p]*ac0[p] - s_mrs[p]*B0 + A0;
        float v1 = s_rs[p]*ac1[p] - s_mrs[p]*B1 + A1;
        float v2 = s_rs[p]*ac2[p] - s_mrs[p]*B2 + A2;
        float v3 = s_rs[p]*ac3[p] - s_mrs[p]*B3 + A3;
        h2[op]        = v0;
        h2[op + H_]   = v1;
        h2[op + 2*H_] = v2;
        h2[op + 3*H_] = v3;
        sp[p] += v0+v1+v2+v3;
        qp[p] += v0*v0+v1*v1+v2*v2+v3*v3;
    }
    #pragma unroll
    for (int p = 0; p < P_; ++p) {
        float s = sp[p], q = qp[p];
        for (int off = 32; off; off >>= 1) { s += __shfl_down(s, off); q += __shfl_down(q, off); }
        if (!lane) { red[wid][p][0] = s; red[wid][p][1] = q; }
    }
    __syncthreads();
    if (threadIdx.x < P_*2) {
        int p = threadIdx.x >> 1, c = threadIdx.x & 1;
        float v = red[0][p][c] + red[1][p][c] + red[2][p][c] + red[3][p][c];
        pC[(((b*P_ + p) << 7) + chunk)*2 + c] = v;
    }
}

// ---- k4: fused LN2 finalize + LN2 + 1x1 conv over P, in place on d_out ----
__global__ __launch_bounds__(256) void k_mix(float* __restrict__ h2,
                                             const float* __restrict__ tw,
                                             const float* __restrict__ tb,
                                             const float* __restrict__ cw,
                                             const float* __restrict__ cb,
                                             const float* __restrict__ pC) {
    __shared__ float scw[P_*P_], scb[P_], sm[P_], sr[P_], srow[P_];
    int b     = blockIdx.x >> 7;
    int chunk = blockIdx.x & 127;
    int tid   = threadIdx.x;
    int wid   = tid >> 6, lane = tid & 63;
    if (tid < P_*P_) scw[tid] = cw[tid];
    if (tid < P_) scb[tid] = cb[tid];
    // fused LN2 finalize: wave wid handles planes wid*3..wid*3+2
    #pragma unroll
    for (int pp = 0; pp < 3; ++pp) {
        int p = wid*3 + pp;
        int g = b*P_ + p;
        float s = pC[((g<<7) + lane)*2]     + pC[((g<<7) + 64 + lane)*2];
        float q = pC[((g<<7) + lane)*2 + 1] + pC[((g<<7) + 64 + lane)*2 + 1];
        for (int off = 32; off; off >>= 1) { s += __shfl_down(s, off); q += __shfl_down(q, off); }
        if (!lane) {
            float m = s * (1.0f/NH_);
            sm[p] = m;
            sr[p] = rsqrtf(q * (1.0f/NH_) - m*m + 1e-5f);
        }
    }
    __syncthreads();
    if (tid < P_) {
        float rs = 0.f;
        #pragma unroll
        for (int p = 0; p < P_; ++p) rs += scw[tid*P_ + p];
        srow[tid] = rs;
    }
    __syncthreads();
    int elem4 = chunk*256 + tid;           // 0..32767 = NH_/4
    size_t base = (size_t)b * P_ * NH_;
    float4 v[P_];
    #pragma unroll
    for (int p = 0; p < P_; ++p) {
        float4 t = *(const float4*)(h2 + base + (size_t)p*NH_ + (size_t)elem4*4);
        float m = sm[p], r = sr[p];
        v[p].x = (t.x-m)*r; v[p].y = (t.y-m)*r; v[p].z = (t.z-m)*r; v[p].w = (t.w-m)*r;
    }
    float4 tw4 = *(const float4*)(tw + (size_t)elem4*4);
    float4 tb4 = *(const float4*)(tb + (size_t)elem4*4);
    #pragma unroll
    for (int q = 0; q < P_; ++q) {
        float4 a = {0.f,0.f,0.f,0.f};
        #pragma unroll
        for (int p = 0; p < P_; ++p) {
            float c = scw[q*P_ + p];
            a.x += c*v[p].x; a.y += c*v[p].y; a.z += c*v[p].z; a.w += c*v[p].w;
        }
        float rb = srow[q], cbq = scb[q];
        float4 o;
        o.x = tw4.x*a.x + tb4.x*rb + cbq;
        o.y = tw4.y*a.y + tb4.y*rb + cbq;
        o.z = tw4.z*a.z + tb4.z*rb + cbq;
        o.w = tw4.w*a.w + tb4.w*rb + cbq;
        *(float4*)(h2 + base + (size_t)q*NH_ + (size_t)elem4*4) = o;
    }
}

extern "C" void kernel_launch(void* const* d_in, const int* in_sizes, int n_in,
                              void* d_out, int out_size, void* d_ws, size_t ws_size,
                              hipStream_t stream) {
    const float* x  = (const float*)d_in[0];
    const int*   ew = (const int*)d_in[1];
    const float* gw = (const float*)d_in[2];
    const float* gb = (const float*)d_in[3];
    const float* tw = (const float*)d_in[4];
    const float* tb = (const float*)d_in[5];
    const float* cw = (const float*)d_in[6];
    const float* cb = (const float*)d_in[7];
    float* out = (float*)d_out;
    float* wf  = (float*)d_ws;

    float* mean1  = wf + WS_MEAN1;
    float* rstd1  = wf + WS_RSTD1;
    float* pA     = wf + WS_PA;
    float* Ag     = wf + WS_AG;
    float* Bg     = wf + WS_BG;
    float* pC     = wf + WS_PC;
    int*   rowPtr = (int*)(wf + WS_ROWPTR);
    int2*  pair   = (int2*)(wf + WS_PAIR);

    k_stats_csr<<<769, 1024, 0, stream>>>(x, ew, pA, rowPtr, pair);
    k_ab<<<513, 256, 0, stream>>>(gw, gb, rowPtr, pair, pA, Ag, Bg, mean1, rstd1);
    k_gather<<<2048, 256, 0, stream>>>(x, mean1, rstd1, rowPtr, pair, Ag, Bg, out, pC);
    k_mix<<<2048, 256, 0, stream>>>(out, tw, tb, cw, cb, pC);
}

// Round 8
// 343.134 us; speedup vs baseline: 1.1249x; 1.1069x over previous
//
#include <hip/hip_runtime.h>

#define B_ 16
#define P_ 12
#define N_ 2048
#define H_ 64
#define E_ 16384
#define NH_ (N_*H_)            // 131072
#define NG_ (B_*P_)            // 192

// ws layout (float offsets)
#define WS_MEAN1  0           // 192
#define WS_RSTD1  192         // 192
#define WS_PA     384         // 768*2 = 1536 -> ends 1920
#define WS_AG     2048        // 131072
#define WS_BG     133120      // 131072 -> ends 264192
#define WS_PC     264192      // 192*128*2 = 49152 -> ends 313344
#define WS_ROWPTR 313344      // 2049 ints -> ends 315393
#define WS_PAIR   315400      // 16384 int2 = 32768 ints -> ends 348168 (8B aligned)

// ---- k1: LN1 partial stats (blocks 0..767, 4 segs/plane) + CSR build (block 768) ----
__global__ __launch_bounds__(1024) void k_stats_csr(const float* __restrict__ x,
                                                    const int* __restrict__ ew,
                                                    float* __restrict__ pA,
                                                    int* __restrict__ rowPtr,
                                                    int2* __restrict__ pair) {
    __shared__ int   sDeg[N_];
    __shared__ int   sA[N_];
    __shared__ int   sB[N_];
    __shared__ float sDinv[N_];
    __shared__ int   sFlag;
    __shared__ float ls[16], lq[16];
    int tid = threadIdx.x;
    if (blockIdx.x < 768) {
        int g = blockIdx.x >> 2, seg = blockIdx.x & 3;
        const float4* xg = (const float4*)(x + (size_t)g * NH_);
        float s = 0.f, q = 0.f;
        int base = seg * 8192;
        #pragma unroll
        for (int i = 0; i < 8; ++i) {
            float4 v = xg[base + i*1024 + tid];
            s += v.x + v.y + v.z + v.w;
            q += v.x*v.x + v.y*v.y + v.z*v.z + v.w*v.w;
        }
        for (int off = 32; off; off >>= 1) { s += __shfl_down(s, off); q += __shfl_down(q, off); }
        int wid = tid >> 6, lane = tid & 63;
        if (!lane) { ls[wid] = s; lq[wid] = q; }
        __syncthreads();
        if (!tid) {
            float S = 0.f, Q = 0.f;
            #pragma unroll
            for (int i = 0; i < 16; ++i) { S += ls[i]; Q += lq[i]; }
            pA[blockIdx.x*2]   = S;
            pA[blockIdx.x*2+1] = Q;
        }
        return;
    }
    // ---- CSR build with int32/int64 detection ----
    if (!tid) sFlag = 1;
    for (int i = tid; i < N_; i += 1024) sDeg[i] = 0;
    __syncthreads();
    if (tid < 256) { if (ew[2*tid+1] != 0) atomicAnd(&sFlag, 0); }
    __syncthreads();
    int is64 = sFlag;
    for (int e = tid; e < E_; e += 1024) {
        int dst = is64 ? ew[2*(E_+e)] : ew[E_+e];
        atomicAdd(&sDeg[dst], 1);
    }
    __syncthreads();
    for (int i = tid; i < N_; i += 1024) {
        int d = sDeg[i];
        sDinv[i] = d > 0 ? rsqrtf((float)d) : 0.f;
        sA[i] = d;
    }
    __syncthreads();
    int* in = sA; int* out = sB;
    for (int st = 1; st < N_; st <<= 1) {
        for (int i = tid; i < N_; i += 1024) {
            int v = in[i];
            if (i >= st) v += in[i-st];
            out[i] = v;
        }
        __syncthreads();
        int* t = in; in = out; out = t;
    }
    for (int i = tid; i < N_; i += 1024) {
        int excl = in[i] - sDeg[i];
        rowPtr[i] = excl;
        out[i] = excl;
    }
    if (!tid) rowPtr[N_] = E_;
    __syncthreads();
    for (int e = tid; e < E_; e += 1024) {
        int src = is64 ? ew[2*e]       : ew[e];
        int dst = is64 ? ew[2*(E_+e)]  : ew[E_+e];
        int pos = atomicAdd(&out[dst], 1);
        int2 pr; pr.x = src; pr.y = __float_as_int(sDinv[src] * sDinv[dst]);
        pair[pos] = pr;
    }
}

// ---- k2: per-node A/B rows (blocks 0..511, wave per node) + LN1 finalize (block 512) ----
__global__ __launch_bounds__(256) void k_ab(const float* __restrict__ gw,
                                            const float* __restrict__ gb,
                                            const int* __restrict__ rowPtr,
                                            const int2* __restrict__ pair,
                                            const float* __restrict__ pA,
                                            float* __restrict__ Ag,
                                            float* __restrict__ Bg,
                                            float* __restrict__ mean1,
                                            float* __restrict__ rstd1) {
    int tid = threadIdx.x;
    if (blockIdx.x == 512) {
        if (tid < NG_) {
            float s = 0.f, q = 0.f;
            #pragma unroll
            for (int i = 0; i < 4; ++i) {
                s += pA[(tid*4+i)*2];
                q += pA[(tid*4+i)*2+1];
            }
            float m = s * (1.0f/NH_);
            float v = q * (1.0f/NH_) - m*m;
            mean1[tid] = m;
            rstd1[tid] = rsqrtf(v + 1e-5f);
        }
        return;
    }
    int wid = tid >> 6, lane = tid & 63;
    int n = blockIdx.x*4 + wid;
    int j = rowPtr[n], e = rowPtr[n+1];
    float A = 0.f, Bv = 0.f;
    for (; j < e; ++j) {
        int2 pr = pair[j];
        float w = __int_as_float(pr.y);
        int ro = pr.x*H_ + lane;
        A  += w * gb[ro];
        Bv += w * gw[ro];
    }
    Ag[n*H_ + lane] = A;
    Bg[n*H_ + lane] = Bv;
}

// ---- k3: gather v6 — quad-plane float4 layout ----
// lane=(q,k): q=lane>>4, k=lane&15. Lane owns h-chunk 4k..4k+3 of planes {q,q+4,q+8}.
// Per edge: 1 wave-uniform pair load + 3 float4 load insts (1KB each, 4 planes/inst).
// h2[b,p,n,h] = rs[p]*acc_p - mrs[p]*B[n,h] + A[n,h]
__global__ __launch_bounds__(256) void k_gather(const float* __restrict__ x,
                                                const float* __restrict__ mean1,
                                                const float* __restrict__ rstd1,
                                                const int* __restrict__ rowPtr,
                                                const int2* __restrict__ pair,
                                                const float* __restrict__ Ag,
                                                const float* __restrict__ Bg,
                                                float* __restrict__ h2,
                                                float* __restrict__ pC) {
    int b     = blockIdx.x & 15;
    int chunk = blockIdx.x >> 4;           // 0..127
    int tid   = threadIdx.x;
    int wid   = tid >> 6, lane = tid & 63;
    int q     = lane >> 4, k = lane & 15;
    __shared__ float s_rs[P_], s_mrs[P_];
    __shared__ float red[4][P_][2];
    if (tid < P_) {
        float m = mean1[b*P_ + tid], r = rstd1[b*P_ + tid];
        s_rs[tid] = r; s_mrs[tid] = m*r;
    }
    __syncthreads();
    float rs0 = s_rs[q],  rs1 = s_rs[q+4],  rs2 = s_rs[q+8];
    float ms0 = s_mrs[q], ms1 = s_mrs[q+4], ms2 = s_mrs[q+8];
    const float* xb  = x + (size_t)b * P_ * NH_;
    const float* xp0 = xb + (size_t)q     * NH_;
    const float* xp1 = xb + (size_t)(q+4) * NH_;
    const float* xp2 = xb + (size_t)(q+8) * NH_;
    int hh = k*4;
    float sp0=0.f, sp1=0.f, sp2=0.f, qp0=0.f, qp1=0.f, qp2=0.f;
    #pragma unroll
    for (int i = 0; i < 4; ++i) {
        int n  = chunk*16 + wid*4 + i;
        int r0 = rowPtr[n], r1 = rowPtr[n+1];
        float4 a0 = {0,0,0,0}, a1 = {0,0,0,0}, a2 = {0,0,0,0};
        #pragma unroll 2
        for (int j = r0; j < r1; ++j) {
            int2 pr = pair[j];
            float w = __int_as_float(pr.y);
            int ro = pr.x*H_ + hh;
            float4 x0 = *(const float4*)(xp0 + ro);
            float4 x1 = *(const float4*)(xp1 + ro);
            float4 x2 = *(const float4*)(xp2 + ro);
            a0.x += w*x0.x; a0.y += w*x0.y; a0.z += w*x0.z; a0.w += w*x0.w;
            a1.x += w*x1.x; a1.y += w*x1.y; a1.z += w*x1.z; a1.w += w*x1.w;
            a2.x += w*x2.x; a2.y += w*x2.y; a2.z += w*x2.z; a2.w += w*x2.w;
        }
        float4 A4 = *(const float4*)(Ag + n*H_ + hh);
        float4 B4 = *(const float4*)(Bg + n*H_ + hh);
        float4 v0, v1, v2;
        v0.x = rs0*a0.x - ms0*B4.x + A4.x;  v0.y = rs0*a0.y - ms0*B4.y + A4.y;
        v0.z = rs0*a0.z - ms0*B4.z + A4.z;  v0.w = rs0*a0.w - ms0*B4.w + A4.w;
        v1.x = rs1*a1.x - ms1*B4.x + A4.x;  v1.y = rs1*a1.y - ms1*B4.y + A4.y;
        v1.z = rs1*a1.z - ms1*B4.z + A4.z;  v1.w = rs1*a1.w - ms1*B4.w + A4.w;
        v2.x = rs2*a2.x - ms2*B4.x + A4.x;  v2.y = rs2*a2.y - ms2*B4.y + A4.y;
        v2.z = rs2*a2.z - ms2*B4.z + A4.z;  v2.w = rs2*a2.w - ms2*B4.w + A4.w;
        size_t bn = (size_t)b*P_*NH_ + (size_t)n*H_ + hh;
        *(float4*)(h2 + bn + (size_t)q    *NH_) = v0;
        *(float4*)(h2 + bn + (size_t)(q+4)*NH_) = v1;
        *(float4*)(h2 + bn + (size_t)(q+8)*NH_) = v2;
        sp0 += v0.x+v0.y+v0.z+v0.w;  qp0 += v0.x*v0.x+v0.y*v0.y+v0.z*v0.z+v0.w*v0.w;
        sp1 += v1.x+v1.y+v1.z+v1.w;  qp1 += v1.x*v1.x+v1.y*v1.y+v1.z*v1.z+v1.w*v1.w;
        sp2 += v2.x+v2.y+v2.z+v2.w;  qp2 += v2.x*v2.x+v2.y*v2.y+v2.z*v2.z+v2.w*v2.w;
    }
    // reduce over the 16 lanes of each quad
    #pragma unroll
    for (int off = 1; off < 16; off <<= 1) {
        sp0 += __shfl_xor(sp0, off); qp0 += __shfl_xor(qp0, off);
        sp1 += __shfl_xor(sp1, off); qp1 += __shfl_xor(qp1, off);
        sp2 += __shfl_xor(sp2, off); qp2 += __shfl_xor(qp2, off);
    }
    if (k == 0) {
        red[wid][q  ][0] = sp0; red[wid][q  ][1] = qp0;
        red[wid][q+4][0] = sp1; red[wid][q+4][1] = qp1;
        red[wid][q+8][0] = sp2; red[wid][q+8][1] = qp2;
    }
    __syncthreads();
    if (tid < P_*2) {
        int p = tid >> 1, c = tid & 1;
        float v = red[0][p][c] + red[1][p][c] + red[2][p][c] + red[3][p][c];
        pC[(((b*P_ + p) << 7) + chunk)*2 + c] = v;
    }
}

// ---- k4: fused LN2 finalize + LN2 + 1x1 conv over P, in place on d_out ----
__global__ __launch_bounds__(256) void k_mix(float* __restrict__ h2,
                                             const float* __restrict__ tw,
                                             const float* __restrict__ tb,
                                             const float* __restrict__ cw,
                                             const float* __restrict__ cb,
                                             const float* __restrict__ pC) {
    __shared__ float scw[P_*P_], scb[P_], sm[P_], sr[P_], srow[P_];
    int b     = blockIdx.x >> 7;
    int chunk = blockIdx.x & 127;
    int tid   = threadIdx.x;
    int wid   = tid >> 6, lane = tid & 63;
    if (tid < P_*P_) scw[tid] = cw[tid];
    if (tid < P_) scb[tid] = cb[tid];
    // fused LN2 finalize: wave wid handles planes wid*3..wid*3+2
    #pragma unroll
    for (int pp = 0; pp < 3; ++pp) {
        int p = wid*3 + pp;
        int g = b*P_ + p;
        float s = pC[((g<<7) + lane)*2]     + pC[((g<<7) + 64 + lane)*2];
        float q = pC[((g<<7) + lane)*2 + 1] + pC[((g<<7) + 64 + lane)*2 + 1];
        for (int off = 32; off; off >>= 1) { s += __shfl_down(s, off); q += __shfl_down(q, off); }
        if (!lane) {
            float m = s * (1.0f/NH_);
            sm[p] = m;
            sr[p] = rsqrtf(q * (1.0f/NH_) - m*m + 1e-5f);
        }
    }
    __syncthreads();
    if (tid < P_) {
        float rs = 0.f;
        #pragma unroll
        for (int p = 0; p < P_; ++p) rs += scw[tid*P_ + p];
        srow[tid] = rs;
    }
    __syncthreads();
    int elem4 = chunk*256 + tid;           // 0..32767 = NH_/4
    size_t base = (size_t)b * P_ * NH_;
    float4 v[P_];
    #pragma unroll
    for (int p = 0; p < P_; ++p) {
        float4 t = *(const float4*)(h2 + base + (size_t)p*NH_ + (size_t)elem4*4);
        float m = sm[p], r = sr[p];
        v[p].x = (t.x-m)*r; v[p].y = (t.y-m)*r; v[p].z = (t.z-m)*r; v[p].w = (t.w-m)*r;
    }
    float4 tw4 = *(const float4*)(tw + (size_t)elem4*4);
    float4 tb4 = *(const float4*)(tb + (size_t)elem4*4);
    #pragma unroll
    for (int q = 0; q < P_; ++q) {
        float4 a = {0.f,0.f,0.f,0.f};
        #pragma unroll
        for (int p = 0; p < P_; ++p) {
            float c = scw[q*P_ + p];
            a.x += c*v[p].x; a.y += c*v[p].y; a.z += c*v[p].z; a.w += c*v[p].w;
        }
        float rb = srow[q], cbq = scb[q];
        float4 o;
        o.x = tw4.x*a.x + tb4.x*rb + cbq;
        o.y = tw4.y*a.y + tb4.y*rb + cbq;
        o.z = tw4.z*a.z + tb4.z*rb + cbq;
        o.w = tw4.w*a.w + tb4.w*rb + cbq;
        *(float4*)(h2 + base + (size_t)q*NH_ + (size_t)elem4*4) = o;
    }
}

extern "C" void kernel_launch(void* const* d_in, const int* in_sizes, int n_in,
                              void* d_out, int out_size, void* d_ws, size_t ws_size,
                              hipStream_t stream) {
    const float* x  = (const float*)d_in[0];
    const int*   ew = (const int*)d_in[1];
    const float* gw = (const float*)d_in[2];
    const float* gb = (const float*)d_in[3];
    const float* tw = (const float*)d_in[4];
    const float* tb = (const float*)d_in[5];
    const float* cw = (const float*)d_in[6];
    const float* cb = (const float*)d_in[7];
    float* out = (float*)d_out;
    float* wf  = (float*)d_ws;

    float* mean1  = wf + WS_MEAN1;
    float* rstd1  = wf + WS_RSTD1;
    float* pA     = wf + WS_PA;
    float* Ag     = wf + WS_AG;
    float* Bg     = wf + WS_BG;
    float* pC     = wf + WS_PC;
    int*   rowPtr = (int*)(wf + WS_ROWPTR);
    int2*  pair   = (int2*)(wf + WS_PAIR);

    k_stats_csr<<<769, 1024, 0, stream>>>(x, ew, pA, rowPtr, pair);
    k_ab<<<513, 256, 0, stream>>>(gw, gb, rowPtr, pair, pA, Ag, Bg, mean1, rstd1);
    k_gather<<<2048, 256, 0, stream>>>(x, mean1, rstd1, rowPtr, pair, Ag, Bg, out, pC);
    k_mix<<<2048, 256, 0, stream>>>(out, tw, tb, cw, cb, pC);
}